// Round 6
// baseline (73.517 us; speedup 1.0000x reference)
//
#include <hip/hip_runtime.h>
#include <hip/hip_fp16.h>

#define IN_F   4096
#define OUT_F  11008
#define BATCH  16
#define GROUPS 32                    // 4096 / 128
#define PACKED_PER_ROW (IN_F / 2)    // 2048 int32 per output row

typedef __attribute__((ext_vector_type(8))) _Float16 half8;
typedef __attribute__((ext_vector_type(4))) _Float16 half4;
typedef __attribute__((ext_vector_type(2))) _Float16 h2;
typedef __attribute__((ext_vector_type(4))) float    float4_t;
typedef __attribute__((ext_vector_type(4))) int      int4_t;
typedef __attribute__((ext_vector_type(4))) unsigned uint4_t;

__device__ inline h2 cvt2(float a, float b) {
    return __builtin_bit_cast(h2, __builtin_amdgcn_cvt_pkrtz(a, b));
}

// ---- pre-pass: x (16x4096 f32) -> f16 table in workspace (128 KB) ----
__global__ __launch_bounds__(256) void xcvt(const float* __restrict__ x,
                                            _Float16* __restrict__ xh) {
    const int i = (blockIdx.x * 256 + threadIdx.x) * 4;   // 64 blocks cover 65536
    const float4_t v = *(const float4_t*)(x + i);
    half4 h;
    h2 lo = cvt2(v.x, v.y), hi = cvt2(v.z, v.w);
    h[0] = lo[0]; h[1] = lo[1]; h[2] = hi[0]; h[3] = hi[1];
    *(half4*)(xh + i) = h;
}

// ---- main kernel: DIAGNOSTIC build — identical R5 structure, but the whole
// body repeats 3x (memory-clobber between reps prevents CSE; same values
// stored each rep, so output is unchanged). Purpose: push this dispatch's
// duration above the harness's 51-us fillBuffer poisons so it surfaces in
// the top-5 rocprof rows with VGPR/Occupancy/VALUBusy/FETCH_SIZE visible.
__global__ __launch_bounds__(64) void gptq_gemm_w(
    const _Float16* __restrict__ xh, const int* __restrict__ qw,
    const float* __restrict__ scales, const float* __restrict__ zeros,
    float* __restrict__ ws_part)
{
    const int lane  = threadIdx.x;       // 0..63
    const int otile = blockIdx.x >> 2;
    const int kq    = blockIdx.x & 3;

    const int ln = lane & 15;            // o within tile / x row select
    const int lk = lane >> 4;            // k-subchunk 0..3
    const int o  = otile * 16 + ln;

    const int*      qbase = qw + o * PACKED_PER_ROW + kq * 512 + lk * 4;
    const _Float16* xbase = xh + ln * IN_F + kq * 1024 + lk * 8;

    const float4_t sf0 = *(const float4_t*)(scales + o * GROUPS + kq * 8);
    const float4_t sf1 = *(const float4_t*)(scales + o * GROUPS + kq * 8 + 4);
    const float4_t zf0 = *(const float4_t*)(zeros  + o * GROUPS + kq * 8);
    const float4_t zf1 = *(const float4_t*)(zeros  + o * GROUPS + kq * 8 + 4);
    const float sArr[8] = { sf0.x, sf0.y, sf0.z, sf0.w, sf1.x, sf1.y, sf1.z, sf1.w };
    const float zArr[8] = { zf0.x, zf0.y, zf0.z, zf0.w, zf1.x, zf1.y, zf1.z, zf1.w };

    const h2 k1024 = { (_Float16)1024.0f, (_Float16)1024.0f };

    for (int rep = 0; rep < 3; ++rep) {
        asm volatile("" ::: "memory");   // force real re-loads each rep

        int4_t qv[2][8];
        half8  xv[2][8];
        #pragma unroll
        for (int t = 0; t < 8; ++t) {
            qv[0][t] = *(const int4_t*)(qbase + t * 16);
            xv[0][t] = *(const half8*)(xbase + t * 32);
        }

        float4_t acc = {0.f, 0.f, 0.f, 0.f};

        #pragma unroll
        for (int c = 0; c < 4; ++c) {
            const int cur = c & 1, nxt = cur ^ 1;
            if (c < 3) {
                #pragma unroll
                for (int t = 0; t < 8; ++t) {
                    qv[nxt][t] = *(const int4_t*)(qbase + (c + 1) * 128 + t * 16);
                    xv[nxt][t] = *(const half8*)(xbase + (c + 1) * 256 + t * 32);
                }
            }
            h2 s2[2], c2[2];
            #pragma unroll
            for (int gi = 0; gi < 2; ++gi) {
                const float s  = sArr[2 * c + gi];
                const float c0 = -zArr[2 * c + gi] * s;
                s2[gi] = cvt2(s, s);
                c2[gi] = cvt2(c0, c0);
            }
            #pragma unroll
            for (int t = 0; t < 8; ++t) {
                const int gi = t >> 2;
                uint4_t bw;
                #pragma unroll
                for (int i = 0; i < 4; ++i) {
                    const unsigned pv = (unsigned)qv[cur][t][i];
                    const unsigned u = (pv & 0xFu) | ((pv << 12) & 0xF0000u)
                                     | 0x64006400u;            // {1024+qlo,1024+qhi}
                    h2 q = __builtin_bit_cast(h2, u) - k1024;  // exact {qlo,qhi}
                    h2 w = q * s2[gi] + c2[gi];                // v_pk_fma_f16
                    bw[i] = __builtin_bit_cast(unsigned, w);
                }
                acc = __builtin_amdgcn_mfma_f32_16x16x32_f16(
                    xv[cur][t], __builtin_bit_cast(half8, bw), acc, 0, 0, 0);
            }
        }

        // C/D layout: lane holds D[row=(l>>4)*4+r][col=l&15]; same values
        // every rep -> deterministic, output unchanged.
        #pragma unroll
        for (int r = 0; r < 4; ++r)
            ws_part[(kq * BATCH + lk * 4 + r) * OUT_F + otile * 16 + ln] = acc[r];
    }
}

__global__ __launch_bounds__(256) void gptq_reduce(
    const float* __restrict__ ws_part, const float* __restrict__ bias,
    float* __restrict__ out)
{
    const int idx = blockIdx.x * 256 + threadIdx.x;   // b*OUT_F + o
    if (idx >= BATCH * OUT_F) return;
    const int o = idx % OUT_F;
    out[idx] = bias[o]
             + ws_part[idx]
             + ws_part[1 * (BATCH * OUT_F) + idx]
             + ws_part[2 * (BATCH * OUT_F) + idx]
             + ws_part[3 * (BATCH * OUT_F) + idx];
}

// ---- fallback (no workspace): 4-wave single-pass kernel ----
__global__ __launch_bounds__(256) void gptq_gemm_fb(
    const float* __restrict__ x, const int* __restrict__ qw,
    const float* __restrict__ scales, const float* __restrict__ zeros,
    const float* __restrict__ bias, float* __restrict__ out)
{
    const int tid  = threadIdx.x;
    const int lane = tid & 63;
    const int wave = tid >> 6;
    const int otile = blockIdx.x;
    const int ln = lane & 15, lk = lane >> 4;
    const int o = otile * 16 + ln;
    const int kc0 = wave * 1024;

    const int* qbase = qw + o * PACKED_PER_ROW + (kc0 >> 1) + lk * 4;
    const float* srow = scales + o * GROUPS;
    const float* zrow = zeros  + o * GROUPS;

    float4_t acc = {0.f, 0.f, 0.f, 0.f};
    const h2 k1024 = { (_Float16)1024.0f, (_Float16)1024.0f };

    #pragma unroll
    for (int ch = 0; ch < 4; ++ch) {
        const int cc = kc0 + ch * 256;
        h2 s2[2], c2[2];
        #pragma unroll
        for (int gi = 0; gi < 2; ++gi) {
            const float s  = srow[(cc >> 7) + gi];
            const float c0 = -zrow[(cc >> 7) + gi] * s;
            s2[gi] = cvt2(s, s); c2[gi] = cvt2(c0, c0);
        }
        #pragma unroll
        for (int t = 0; t < 8; ++t) {
            const int4_t v = *(const int4_t*)(qbase + ch * 128 + t * 16);
            const float* xp = x + ln * IN_F + cc + t * 32 + lk * 8;
            const float4_t a0 = *(const float4_t*)(xp);
            const float4_t a1 = *(const float4_t*)(xp + 4);
            half8 af;
            h2 p0 = cvt2(a0.x, a0.y), p1 = cvt2(a0.z, a0.w);
            h2 p2 = cvt2(a1.x, a1.y), p3 = cvt2(a1.z, a1.w);
            af[0]=p0[0]; af[1]=p0[1]; af[2]=p1[0]; af[3]=p1[1];
            af[4]=p2[0]; af[5]=p2[1]; af[6]=p3[0]; af[7]=p3[1];
            const int gi = t >> 2;
            uint4_t bw;
            #pragma unroll
            for (int i = 0; i < 4; ++i) {
                const unsigned pv = (unsigned)v[i];
                const unsigned u = (pv & 0xFu) | ((pv << 12) & 0xF0000u)
                                 | 0x64006400u;
                h2 q = __builtin_bit_cast(h2, u) - k1024;
                h2 w = q * s2[gi] + c2[gi];
                bw[i] = __builtin_bit_cast(unsigned, w);
            }
            acc = __builtin_amdgcn_mfma_f32_16x16x32_f16(
                af, __builtin_bit_cast(half8, bw), acc, 0, 0, 0);
        }
    }

    __shared__ float red[4][16][17];
    #pragma unroll
    for (int r = 0; r < 4; ++r) red[wave][lk * 4 + r][ln] = acc[r];
    __syncthreads();
    const int row = tid >> 4, col = tid & 15;
    const float sum = red[0][row][col] + red[1][row][col]
                    + red[2][row][col] + red[3][row][col];
    const int oo = otile * 16 + col;
    out[row * OUT_F + oo] = sum + bias[oo];
}

extern "C" void kernel_launch(void* const* d_in, const int* in_sizes, int n_in,
                              void* d_out, int out_size, void* d_ws, size_t ws_size,
                              hipStream_t stream) {
    const float* x      = (const float*)d_in[0];
    const int*   qwgt   = (const int*)d_in[1];
    const float* scales = (const float*)d_in[2];
    const float* zeros  = (const float*)d_in[3];
    const float* bias   = (const float*)d_in[4];
    float* out = (float*)d_out;

    const int nOTiles = OUT_F / 16;                    // 688
    const size_t need = (size_t)8 << 20;

    if (d_ws && ws_size >= need) {
        float*    ws_part = (float*)d_ws;                         // 2.75 MB
        _Float16* xh      = (_Float16*)((char*)d_ws + (4 << 20)); // 128 KB
        hipLaunchKernelGGL(xcvt, dim3(BATCH * IN_F / 1024), dim3(256), 0, stream,
                           x, xh);
        hipLaunchKernelGGL(gptq_gemm_w, dim3(nOTiles * 4), dim3(64), 0, stream,
                           xh, qwgt, scales, zeros, ws_part);
        hipLaunchKernelGGL(gptq_reduce, dim3((BATCH * OUT_F + 255) / 256),
                           dim3(256), 0, stream, ws_part, bias, out);
    } else {
        hipLaunchKernelGGL(gptq_gemm_fb, dim3(nOTiles), dim3(256), 0, stream,
                           x, qwgt, scales, zeros, bias, out);
    }
}

// Round 7
// 35.188 us; speedup vs baseline: 2.0893x; 2.0893x over previous
//
#include <hip/hip_runtime.h>
#include <hip/hip_fp16.h>

#define IN_F   4096
#define OUT_F  11008
#define BATCH  16
#define GROUPS 32                    // 4096 / 128
#define PACKED_PER_ROW (IN_F / 2)    // 2048 int32 per output row

typedef __attribute__((ext_vector_type(8))) _Float16 half8;
typedef __attribute__((ext_vector_type(4))) _Float16 half4;
typedef __attribute__((ext_vector_type(2))) _Float16 h2;
typedef __attribute__((ext_vector_type(4))) float    float4_t;
typedef __attribute__((ext_vector_type(4))) int      int4_t;
typedef __attribute__((ext_vector_type(4))) unsigned uint4_t;

__device__ inline h2 cvt2(float a, float b) {
    return __builtin_bit_cast(h2, __builtin_amdgcn_cvt_pkrtz(a, b));
}

// ---- pre-pass: x (16x4096 f32) -> f16 table in workspace (128 KB) ----
__global__ __launch_bounds__(256) void xcvt(const float* __restrict__ x,
                                            _Float16* __restrict__ xh) {
    const int i = (blockIdx.x * 256 + threadIdx.x) * 4;   // 64 blocks cover 65536
    const float4_t v = *(const float4_t*)(x + i);
    half4 h;
    h2 lo = cvt2(v.x, v.y), hi = cvt2(v.z, v.w);
    h[0] = lo[0]; h[1] = lo[1]; h[2] = hi[0]; h[3] = hi[1];
    *(half4*)(xh + i) = h;
}

// ---- main: 1 wave/block; loads via inline-asm (unsinkable) + counted vmcnt.
// R6 diagnostic showed the compiler sank all staging loads (VGPR_Count=32,
// ~1 load in flight, ~700cy serial per load). Here each wave keeps 16-32
// outstanding dwordx4 (16-32 KB) across the whole K-quarter.
__global__ __launch_bounds__(64) void gptq_gemm_w(
    const _Float16* __restrict__ xh, const int* __restrict__ qw,
    const float* __restrict__ scales, const float* __restrict__ zeros,
    float* __restrict__ ws_part)
{
    const int lane  = threadIdx.x;       // 0..63
    const int otile = blockIdx.x >> 2;
    const int kq    = blockIdx.x & 3;

    const int ln = lane & 15;            // o within tile / x row select
    const int lk = lane >> 4;            // k-subchunk 0..3
    const int o  = otile * 16 + ln;

    const int*      qaddr = qw + o * PACKED_PER_ROW + kq * 512 + lk * 4;
    const _Float16* xaddr = xh + ln * IN_F + kq * 1024 + lk * 8;

    // ---- group constants, fully resolved BEFORE the asm pipeline ----
    const float4_t sf0 = *(const float4_t*)(scales + o * GROUPS + kq * 8);
    const float4_t sf1 = *(const float4_t*)(scales + o * GROUPS + kq * 8 + 4);
    const float4_t zf0 = *(const float4_t*)(zeros  + o * GROUPS + kq * 8);
    const float4_t zf1 = *(const float4_t*)(zeros  + o * GROUPS + kq * 8 + 4);
    const float sArr[8] = { sf0.x, sf0.y, sf0.z, sf0.w, sf1.x, sf1.y, sf1.z, sf1.w };
    const float zArr[8] = { zf0.x, zf0.y, zf0.z, zf0.w, zf1.x, zf1.y, zf1.z, zf1.w };
    h2 s2g[8], c2g[8];
    #pragma unroll
    for (int gi = 0; gi < 8; ++gi) {
        const float s  = sArr[gi];
        const float c0 = -zArr[gi] * s;          // w = q*s + c0
        s2g[gi] = cvt2(s, s);
        c2g[gi] = cvt2(c0, c0);
    }

    int4_t qv[2][8];
    half8  xv[2][8];
    const h2 k1024 = { (_Float16)1024.0f, (_Float16)1024.0f };

// one dwordx4 load, literal byte offset; volatile => stays where issued
#define GLQ(B,T,OFF) asm volatile("global_load_dwordx4 %0, %1, off offset:%2" \
                                  : "=v"(qv[B][T]) : "v"(qaddr), "n"(OFF));
#define GLX(B,T,OFF) asm volatile("global_load_dwordx4 %0, %1, off offset:%2" \
                                  : "=v"(xv[B][T]) : "v"(xaddr), "n"(OFF));
// 16 loads of one 256-col chunk (q and x share the same byte offsets)
#define LOAD_CHUNK(B, CB) \
    GLQ(B,0,CB+0)   GLX(B,0,CB+0)   GLQ(B,1,CB+64)  GLX(B,1,CB+64)  \
    GLQ(B,2,CB+128) GLX(B,2,CB+128) GLQ(B,3,CB+192) GLX(B,3,CB+192) \
    GLQ(B,4,CB+256) GLX(B,4,CB+256) GLQ(B,5,CB+320) GLX(B,5,CB+320) \
    GLQ(B,6,CB+384) GLX(B,6,CB+384) GLQ(B,7,CB+448) GLX(B,7,CB+448)

#define VWAIT16 { asm volatile("s_waitcnt vmcnt(16)" ::: "memory"); \
                  __builtin_amdgcn_sched_barrier(0); }
#define VWAIT0  { asm volatile("s_waitcnt vmcnt(0)"  ::: "memory"); \
                  __builtin_amdgcn_sched_barrier(0); }

// dequant + 8 MFMAs for buffer B holding chunk C (groups 2C, 2C+1)
#define COMPUTE(B, C) { \
    _Pragma("unroll") \
    for (int t = 0; t < 8; ++t) { \
        const int gi = 2*(C) + (t >> 2); \
        uint4_t bw; \
        _Pragma("unroll") \
        for (int i = 0; i < 4; ++i) { \
            const unsigned pv = (unsigned)qv[B][t][i]; \
            const unsigned u = (pv & 0xFu) | ((pv << 12) & 0xF0000u) \
                             | 0x64006400u;             /* {1024+qlo,1024+qhi} */ \
            h2 q = __builtin_bit_cast(h2, u) - k1024;   /* exact {qlo,qhi} */ \
            h2 w = q * s2g[gi] + c2g[gi];               /* v_pk_fma_f16 */ \
            bw[i] = __builtin_bit_cast(unsigned, w); \
        } \
        acc = __builtin_amdgcn_mfma_f32_16x16x32_f16( \
            xv[B][t], __builtin_bit_cast(half8, bw), acc, 0, 0, 0); \
    } }

    float4_t acc = {0.f, 0.f, 0.f, 0.f};

    LOAD_CHUNK(0, 0)        // buf0 <- chunk 0   (16 in flight)
    LOAD_CHUNK(1, 512)      // buf1 <- chunk 1   (32 in flight)

    VWAIT16                 // chunk 0 landed (chunk 1 still in flight)
    COMPUTE(0, 0)
    LOAD_CHUNK(0, 1024)     // buf0 <- chunk 2

    VWAIT16                 // chunk 1 landed (chunk 2 in flight)
    COMPUTE(1, 1)
    LOAD_CHUNK(1, 1536)     // buf1 <- chunk 3

    VWAIT16                 // chunk 2 landed (chunk 3 in flight)
    COMPUTE(0, 2)

    VWAIT0                  // chunk 3 landed
    COMPUTE(1, 3)

    // C/D layout (verified): lane holds D[row=(l>>4)*4+r][col=l&15]
    #pragma unroll
    for (int r = 0; r < 4; ++r)
        ws_part[(kq * BATCH + lk * 4 + r) * OUT_F + otile * 16 + ln] = acc[r];

#undef GLQ
#undef GLX
#undef LOAD_CHUNK
#undef VWAIT16
#undef VWAIT0
#undef COMPUTE
}

__global__ __launch_bounds__(256) void gptq_reduce(
    const float* __restrict__ ws_part, const float* __restrict__ bias,
    float* __restrict__ out)
{
    const int idx = blockIdx.x * 256 + threadIdx.x;   // b*OUT_F + o
    if (idx >= BATCH * OUT_F) return;
    const int o = idx % OUT_F;
    out[idx] = bias[o]
             + ws_part[idx]
             + ws_part[1 * (BATCH * OUT_F) + idx]
             + ws_part[2 * (BATCH * OUT_F) + idx]
             + ws_part[3 * (BATCH * OUT_F) + idx];
}

// ---- fallback (no workspace): 4-wave single-pass kernel ----
__global__ __launch_bounds__(256) void gptq_gemm_fb(
    const float* __restrict__ x, const int* __restrict__ qw,
    const float* __restrict__ scales, const float* __restrict__ zeros,
    const float* __restrict__ bias, float* __restrict__ out)
{
    const int tid  = threadIdx.x;
    const int lane = tid & 63;
    const int wave = tid >> 6;
    const int otile = blockIdx.x;
    const int ln = lane & 15, lk = lane >> 4;
    const int o = otile * 16 + ln;
    const int kc0 = wave * 1024;

    const int* qbase = qw + o * PACKED_PER_ROW + (kc0 >> 1) + lk * 4;
    const float* srow = scales + o * GROUPS;
    const float* zrow = zeros  + o * GROUPS;

    float4_t acc = {0.f, 0.f, 0.f, 0.f};
    const h2 k1024 = { (_Float16)1024.0f, (_Float16)1024.0f };

    #pragma unroll
    for (int ch = 0; ch < 4; ++ch) {
        const int cc = kc0 + ch * 256;
        h2 s2[2], c2[2];
        #pragma unroll
        for (int gi = 0; gi < 2; ++gi) {
            const float s  = srow[(cc >> 7) + gi];
            const float c0 = -zrow[(cc >> 7) + gi] * s;
            s2[gi] = cvt2(s, s); c2[gi] = cvt2(c0, c0);
        }
        #pragma unroll
        for (int t = 0; t < 8; ++t) {
            const int4_t v = *(const int4_t*)(qbase + ch * 128 + t * 16);
            const float* xp = x + ln * IN_F + cc + t * 32 + lk * 8;
            const float4_t a0 = *(const float4_t*)(xp);
            const float4_t a1 = *(const float4_t*)(xp + 4);
            half8 af;
            h2 p0 = cvt2(a0.x, a0.y), p1 = cvt2(a0.z, a0.w);
            h2 p2 = cvt2(a1.x, a1.y), p3 = cvt2(a1.z, a1.w);
            af[0]=p0[0]; af[1]=p0[1]; af[2]=p1[0]; af[3]=p1[1];
            af[4]=p2[0]; af[5]=p2[1]; af[6]=p3[0]; af[7]=p3[1];
            const int gi = t >> 2;
            uint4_t bw;
            #pragma unroll
            for (int i = 0; i < 4; ++i) {
                const unsigned pv = (unsigned)v[i];
                const unsigned u = (pv & 0xFu) | ((pv << 12) & 0xF0000u)
                                 | 0x64006400u;
                h2 q = __builtin_bit_cast(h2, u) - k1024;
                h2 w = q * s2[gi] + c2[gi];
                bw[i] = __builtin_bit_cast(unsigned, w);
            }
            acc = __builtin_amdgcn_mfma_f32_16x16x32_f16(
                af, __builtin_bit_cast(half8, bw), acc, 0, 0, 0);
        }
    }

    __shared__ float red[4][16][17];
    #pragma unroll
    for (int r = 0; r < 4; ++r) red[wave][lk * 4 + r][ln] = acc[r];
    __syncthreads();
    const int row = tid >> 4, col = tid & 15;
    const float sum = red[0][row][col] + red[1][row][col]
                    + red[2][row][col] + red[3][row][col];
    const int oo = otile * 16 + col;
    out[row * OUT_F + oo] = sum + bias[oo];
}

extern "C" void kernel_launch(void* const* d_in, const int* in_sizes, int n_in,
                              void* d_out, int out_size, void* d_ws, size_t ws_size,
                              hipStream_t stream) {
    const float* x      = (const float*)d_in[0];
    const int*   qwgt   = (const int*)d_in[1];
    const float* scales = (const float*)d_in[2];
    const float* zeros  = (const float*)d_in[3];
    const float* bias   = (const float*)d_in[4];
    float* out = (float*)d_out;

    const int nOTiles = OUT_F / 16;                    // 688
    const size_t need = (size_t)8 << 20;

    if (d_ws && ws_size >= need) {
        float*    ws_part = (float*)d_ws;                         // 2.75 MB
        _Float16* xh      = (_Float16*)((char*)d_ws + (4 << 20)); // 128 KB
        hipLaunchKernelGGL(xcvt, dim3(BATCH * IN_F / 1024), dim3(256), 0, stream,
                           x, xh);
        hipLaunchKernelGGL(gptq_gemm_w, dim3(nOTiles * 4), dim3(64), 0, stream,
                           xh, qwgt, scales, zeros, ws_part);
        hipLaunchKernelGGL(gptq_reduce, dim3((BATCH * OUT_F + 255) / 256),
                           dim3(256), 0, stream, ws_part, bias, out);
    } else {
        hipLaunchKernelGGL(gptq_gemm_fb, dim3(nOTiles), dim3(256), 0, stream,
                           x, qwgt, scales, zeros, bias, out);
    }
}

// Round 8
// 30.609 us; speedup vs baseline: 2.4018x; 1.1496x over previous
//
#include <hip/hip_runtime.h>
#include <hip/hip_fp16.h>

#define IN_F   4096
#define OUT_F  11008
#define BATCH  16
#define GROUPS 32                    // 4096 / 128
#define PPR    2048                  // packed int32 per output row (IN_F/2)

typedef __attribute__((ext_vector_type(8))) _Float16 half8;
typedef __attribute__((ext_vector_type(2))) _Float16 h2;
typedef __attribute__((ext_vector_type(4))) float    float4_t;
typedef __attribute__((ext_vector_type(4))) int      int4_t;
typedef __attribute__((ext_vector_type(4))) unsigned uint4_t;

__device__ inline h2 cvt2(float a, float b) {
    return __builtin_bit_cast(h2, __builtin_amdgcn_cvt_pkrtz(a, b));
}

// async global->LDS, 16B per lane, dest = uniform base + lane*16
#define GLOAD_LDS(srcp, ldsp) \
    __builtin_amdgcn_global_load_lds( \
        (const __attribute__((address_space(1))) void*)(srcp), \
        (__attribute__((address_space(3))) void*)(ldsp), 16, 0, 0)

// ---- pre-pass: x (16x4096 f32) -> f16 table in FRAGMENT order ----
// step s (32 k-cols), lane l: xp[s*512 + l*8 .. +8) = f16 x[b=l&15]
// [k = s*32 + (l>>4)*8 .. +8).  In the gemm, a wave's A-fragment load is
// then ONE contiguous 1KB request: xp + s*512 + lane*8.
__global__ __launch_bounds__(256) void xcvt_perm(const float* __restrict__ x,
                                                 _Float16* __restrict__ xp) {
    const int T = blockIdx.x * 256 + threadIdx.x;   // 8192 threads
    const int step = T >> 6, lane = T & 63;
    const int b = lane & 15, k = step * 32 + (lane >> 4) * 8;
    const float4_t a0 = *(const float4_t*)(x + b * IN_F + k);
    const float4_t a1 = *(const float4_t*)(x + b * IN_F + k + 4);
    half8 h;
    h2 p0 = cvt2(a0.x, a0.y), p1 = cvt2(a0.z, a0.w);
    h2 p2 = cvt2(a1.x, a1.y), p3 = cvt2(a1.z, a1.w);
    h[0]=p0[0]; h[1]=p0[1]; h[2]=p1[0]; h[3]=p1[1];
    h[4]=p2[0]; h[5]=p2[1]; h[6]=p3[0]; h[7]=p3[1];
    *(half8*)(xp + step * 512 + lane * 8) = h;
}

// ---- main: 4-wave block = one otile (16 o-rows) x one K-quarter (1024 cols).
// q staged via global_load_lds: every staging instruction is a contiguous
// 1KB segment of one qweight row (16 contiguous lines, vs 16 scattered lines
// in R3-R7 -> attacks the per-CU line-request cap). LDS tile [16][512] int32,
// XOR-swizzled at 16B-slot granularity (slot ^= row&7) via the GLOBAL source
// (T21: linear dest + inv-swizzled src + swizzled ds_read) so fragment
// ds_read_b128 is near-conflict-free. Wave w computes 256-col chunk w.
__global__ __launch_bounds__(256) void gptq_gemm_w(
    const _Float16* __restrict__ xp, const int* __restrict__ qw,
    const float* __restrict__ scales, const float* __restrict__ zeros,
    float* __restrict__ ws_part)
{
    __shared__ int   lq[16 * 512];       // 32 KB swizzled q tile
    __shared__ float red[4][16][17];

    const int tid  = threadIdx.x;
    const int lane = tid & 63, wave = tid >> 6;
    const int otile = blockIdx.x >> 2, kq = blockIdx.x & 3;
    const int ln = lane & 15, lk = lane >> 4;
    const int o  = otile * 16 + ln;

    // ---- stage half 0 (cols [0,256) of each row): wave stages 4 rows ----
    #pragma unroll
    for (int i = 0; i < 4; ++i) {
        const int row = wave * 4 + i;
        const int* src = qw + (otile * 16 + row) * PPR + kq * 512
                       + ((lane ^ (row & 7)) * 4);          // inv-swizzle src
        GLOAD_LDS(src, &lq[row * 512]);
    }

    // group constants for this wave's chunk (c = wave): groups 2c, 2c+1
    const int c = wave;
    const int g = kq * 8 + c * 2;
    const float s0 = scales[o * GROUPS + g], s1 = scales[o * GROUPS + g + 1];
    const float z0 = zeros [o * GROUPS + g], z1 = zeros [o * GROUPS + g + 1];
    const h2 s2[2] = { cvt2(s0, s0), cvt2(s1, s1) };
    const h2 c2[2] = { cvt2(-z0 * s0, -z0 * s0), cvt2(-z1 * s1, -z1 * s1) };
    const h2 k1024 = { (_Float16)1024.0f, (_Float16)1024.0f };
    const int x3 = ln & 7;

    float4_t acc = {0.f, 0.f, 0.f, 0.f};

// chunk C from LDS: 8 fragments; q via swizzled ds_read_b128, x contiguous
#define COMPUTE(C) { \
    _Pragma("unroll") \
    for (int t = 0; t < 8; ++t) { \
        const int4_t v = *(const int4_t*)((const char*)lq + ln * 2048 \
                        + (((C) * 32 + ((t * 4 + lk) ^ x3)) << 4)); \
        const half8 af = *(const half8*)(xp + (kq * 32 + (C) * 8 + t) * 512 \
                        + lane * 8); \
        const int gi = t >> 2; \
        uint4_t bw; \
        _Pragma("unroll") \
        for (int i = 0; i < 4; ++i) { \
            const unsigned pv = (unsigned)v[i]; \
            const unsigned u = (pv & 0xFu) | ((pv << 12) & 0xF0000u) \
                             | 0x64006400u;            /* {1024+qlo,1024+qhi} */ \
            h2 q = __builtin_bit_cast(h2, u) - k1024;  /* exact {qlo,qhi} */ \
            h2 w = q * s2[gi] + c2[gi];                /* v_pk_fma_f16 */ \
            bw[i] = __builtin_bit_cast(unsigned, w); \
        } \
        acc = __builtin_amdgcn_mfma_f32_16x16x32_f16( \
            af, __builtin_bit_cast(half8, bw), acc, 0, 0, 0); \
    } }

    __syncthreads();                     // B1: half 0 in LDS

    // ---- stage half 1 (cols [256,512)): overlaps waves 0/1 compute ----
    #pragma unroll
    for (int i = 0; i < 4; ++i) {
        const int row = wave * 4 + i;
        const int* src = qw + (otile * 16 + row) * PPR + kq * 512 + 256
                       + ((lane ^ (row & 7)) * 4);
        GLOAD_LDS(src, &lq[row * 512 + 256]);
    }

    if (wave < 2) COMPUTE(c)             // chunks 0,1 live in half 0

    __syncthreads();                     // B2: half 1 in LDS

    if (wave >= 2) COMPUTE(c)            // chunks 2,3 live in half 1

    // C/D layout (m89-verified): lane holds D[(l>>4)*4 + r][l&15]
    #pragma unroll
    for (int r = 0; r < 4; ++r) red[wave][lk * 4 + r][ln] = acc[r];
    __syncthreads();                     // B3

    const int row = tid >> 4, col = tid & 15;
    const float sum = red[0][row][col] + red[1][row][col]
                    + red[2][row][col] + red[3][row][col];
    ws_part[(kq * BATCH + row) * OUT_F + otile * 16 + col] = sum;
#undef COMPUTE
}

__global__ __launch_bounds__(256) void gptq_reduce(
    const float* __restrict__ ws_part, const float* __restrict__ bias,
    float* __restrict__ out)
{
    const int idx = blockIdx.x * 256 + threadIdx.x;   // b*OUT_F + o
    if (idx >= BATCH * OUT_F) return;
    const int o = idx % OUT_F;
    out[idx] = bias[o]
             + ws_part[idx]
             + ws_part[1 * (BATCH * OUT_F) + idx]
             + ws_part[2 * (BATCH * OUT_F) + idx]
             + ws_part[3 * (BATCH * OUT_F) + idx];
}

// ---- fallback (no workspace): 4-wave single-pass kernel ----
__global__ __launch_bounds__(256) void gptq_gemm_fb(
    const float* __restrict__ x, const int* __restrict__ qw,
    const float* __restrict__ scales, const float* __restrict__ zeros,
    const float* __restrict__ bias, float* __restrict__ out)
{
    const int tid  = threadIdx.x;
    const int lane = tid & 63;
    const int wave = tid >> 6;
    const int otile = blockIdx.x;
    const int ln = lane & 15, lk = lane >> 4;
    const int o = otile * 16 + ln;
    const int kc0 = wave * 1024;

    const int* qbase = qw + o * PPR + (kc0 >> 1) + lk * 4;
    const float* srow = scales + o * GROUPS;
    const float* zrow = zeros  + o * GROUPS;

    float4_t acc = {0.f, 0.f, 0.f, 0.f};
    const h2 k1024 = { (_Float16)1024.0f, (_Float16)1024.0f };

    #pragma unroll
    for (int ch = 0; ch < 4; ++ch) {
        const int cc = kc0 + ch * 256;
        h2 s2[2], c2[2];
        #pragma unroll
        for (int gi = 0; gi < 2; ++gi) {
            const float s  = srow[(cc >> 7) + gi];
            const float c0 = -zrow[(cc >> 7) + gi] * s;
            s2[gi] = cvt2(s, s); c2[gi] = cvt2(c0, c0);
        }
        #pragma unroll
        for (int t = 0; t < 8; ++t) {
            const int4_t v = *(const int4_t*)(qbase + ch * 128 + t * 16);
            const float* xq = x + ln * IN_F + cc + t * 32 + lk * 8;
            const float4_t a0 = *(const float4_t*)(xq);
            const float4_t a1 = *(const float4_t*)(xq + 4);
            half8 af;
            h2 p0 = cvt2(a0.x, a0.y), p1 = cvt2(a0.z, a0.w);
            h2 p2 = cvt2(a1.x, a1.y), p3 = cvt2(a1.z, a1.w);
            af[0]=p0[0]; af[1]=p0[1]; af[2]=p1[0]; af[3]=p1[1];
            af[4]=p2[0]; af[5]=p2[1]; af[6]=p3[0]; af[7]=p3[1];
            const int gi = t >> 2;
            uint4_t bw;
            #pragma unroll
            for (int i = 0; i < 4; ++i) {
                const unsigned pv = (unsigned)v[i];
                const unsigned u = (pv & 0xFu) | ((pv << 12) & 0xF0000u)
                                 | 0x64006400u;
                h2 q = __builtin_bit_cast(h2, u) - k1024;
                h2 w = q * s2[gi] + c2[gi];
                bw[i] = __builtin_bit_cast(unsigned, w);
            }
            acc = __builtin_amdgcn_mfma_f32_16x16x32_f16(
                af, __builtin_bit_cast(half8, bw), acc, 0, 0, 0);
        }
    }

    __shared__ float red[4][16][17];
    #pragma unroll
    for (int r = 0; r < 4; ++r) red[wave][lk * 4 + r][ln] = acc[r];
    __syncthreads();
    const int row = tid >> 4, col = tid & 15;
    const float sum = red[0][row][col] + red[1][row][col]
                    + red[2][row][col] + red[3][row][col];
    const int oo = otile * 16 + col;
    out[row * OUT_F + oo] = sum + bias[oo];
}

extern "C" void kernel_launch(void* const* d_in, const int* in_sizes, int n_in,
                              void* d_out, int out_size, void* d_ws, size_t ws_size,
                              hipStream_t stream) {
    const float* x      = (const float*)d_in[0];
    const int*   qwgt   = (const int*)d_in[1];
    const float* scales = (const float*)d_in[2];
    const float* zeros  = (const float*)d_in[3];
    const float* bias   = (const float*)d_in[4];
    float* out = (float*)d_out;

    const int nOTiles = OUT_F / 16;                    // 688
    const size_t need = (size_t)8 << 20;

    if (d_ws && ws_size >= need) {
        float*    ws_part = (float*)d_ws;                         // 2.75 MB
        _Float16* xp      = (_Float16*)((char*)d_ws + (4 << 20)); // 128 KB
        hipLaunchKernelGGL(xcvt_perm, dim3(32), dim3(256), 0, stream, x, xp);
        hipLaunchKernelGGL(gptq_gemm_w, dim3(nOTiles * 4), dim3(256), 0, stream,
                           xp, qwgt, scales, zeros, ws_part);
        hipLaunchKernelGGL(gptq_reduce, dim3((BATCH * OUT_F + 255) / 256),
                           dim3(256), 0, stream, ws_part, bias, out);
    } else {
        hipLaunchKernelGGL(gptq_gemm_fb, dim3(nOTiles), dim3(256), 0, stream,
                           x, qwgt, scales, zeros, bias, out);
    }
}

// Round 9
// 30.309 us; speedup vs baseline: 2.4256x; 1.0099x over previous
//
#include <hip/hip_runtime.h>
#include <hip/hip_fp16.h>

#define IN_F   4096
#define OUT_F  11008
#define BATCH  16
#define GROUPS 32                    // 4096 / 128
#define PPR    2048                  // packed int32 per output row (IN_F/2)

typedef __attribute__((ext_vector_type(8))) _Float16 half8;
typedef __attribute__((ext_vector_type(2))) _Float16 h2;
typedef __attribute__((ext_vector_type(4))) float    float4_t;
typedef __attribute__((ext_vector_type(4))) int      int4_t;
typedef __attribute__((ext_vector_type(4))) unsigned uint4_t;

__device__ inline h2 cvt2(float a, float b) {
    return __builtin_bit_cast(h2, __builtin_amdgcn_cvt_pkrtz(a, b));
}

// async global->LDS, 16B per lane, dest = uniform base + lane*16
#define GLOAD_LDS(srcp, ldsp) \
    __builtin_amdgcn_global_load_lds( \
        (const __attribute__((address_space(1))) void*)(srcp), \
        (__attribute__((address_space(3))) void*)(ldsp), 16, 0, 0)

// ---- pre-pass: x (16x4096 f32) -> f16 table in FRAGMENT order ----
// step s (32 k-cols), lane l: xp[s*512 + l*8 .. +8) = f16 x[b=l&15]
// [k = s*32 + (l>>4)*8 .. +8). Gemm A-fragment load = ONE contiguous 1KB req.
__global__ __launch_bounds__(256) void xcvt_perm(const float* __restrict__ x,
                                                 _Float16* __restrict__ xp) {
    const int T = blockIdx.x * 256 + threadIdx.x;   // 8192 threads
    const int step = T >> 6, lane = T & 63;
    const int b = lane & 15, k = step * 32 + (lane >> 4) * 8;
    const float4_t a0 = *(const float4_t*)(x + b * IN_F + k);
    const float4_t a1 = *(const float4_t*)(x + b * IN_F + k + 4);
    half8 h;
    h2 p0 = cvt2(a0.x, a0.y), p1 = cvt2(a0.z, a0.w);
    h2 p2 = cvt2(a1.x, a1.y), p3 = cvt2(a1.z, a1.w);
    h[0]=p0[0]; h[1]=p0[1]; h[2]=p1[0]; h[3]=p1[1];
    h[4]=p2[0]; h[5]=p2[1]; h[6]=p3[0]; h[7]=p3[1];
    *(half8*)(xp + step * 512 + lane * 8) = h;
}

// ---- main: 4-wave block = (otile, K-quarter). All VMEM issued up-front in
// pinned order; raw s_barrier + counted vmcnt (no full-drain syncthreads in
// the pipeline). Wave w: phase A = group kq*8+w (128 k-cols from h0),
// phase B = group kq*8+4+w (from h1). q LDS tile [16][512] int32, 16B-slot
// XOR swizzle (slot^=row&7) applied on the GLOBAL source (T21).
__global__ __launch_bounds__(256) void gptq_gemm_w(
    const _Float16* __restrict__ xp, const int* __restrict__ qw,
    const float* __restrict__ scales, const float* __restrict__ zeros,
    float* __restrict__ ws_part)
{
    __shared__ int   lq[16 * 512];       // 32 KB swizzled q tile
    __shared__ float red[4][16][17];

    const int tid  = threadIdx.x;
    const int lane = tid & 63, wave = tid >> 6;
    const int otile = blockIdx.x >> 2, kq = blockIdx.x & 3;
    const int ln = lane & 15, lk = lane >> 4;
    const int o  = otile * 16 + ln;
    const int x3 = ln & 7;

    // group constants FIRST; the vmcnt(0) fence below forces their loads to
    // retire before the counted-vmcnt region (keeps the counts exact).
    const int gA = kq * 8 + wave, gB = gA + 4;
    const float sa = scales[o * GROUPS + gA], za = zeros[o * GROUPS + gA];
    const float sb = scales[o * GROUPS + gB], zb = zeros[o * GROUPS + gB];
    const h2 s2a = cvt2(sa, sa), c2a = cvt2(-za * sa, -za * sa);
    const h2 s2b = cvt2(sb, sb), c2b = cvt2(-zb * sb, -zb * sb);
    const h2 k1024 = { (_Float16)1024.0f, (_Float16)1024.0f };

    asm volatile("s_waitcnt vmcnt(0)" ::: "memory");
    __builtin_amdgcn_sched_barrier(0);

    // ---- pinned issue order: 4 xA | 4 h0-stage | 4 h1-stage ----
    const _Float16* xqa = xp + (kq * 32 + wave * 4) * 512 + lane * 8;
    const _Float16* xqb = xqa + 16 * 512;
    half8 xa0, xa1, xa2, xa3, xb0, xb1, xb2, xb3;
    asm volatile("global_load_dwordx4 %0, %1, off"             : "=v"(xa0) : "v"(xqa));
    asm volatile("global_load_dwordx4 %0, %1, off offset:1024" : "=v"(xa1) : "v"(xqa));
    asm volatile("global_load_dwordx4 %0, %1, off offset:2048" : "=v"(xa2) : "v"(xqa));
    asm volatile("global_load_dwordx4 %0, %1, off offset:3072" : "=v"(xa3) : "v"(xqa));
    __builtin_amdgcn_sched_barrier(0);
    #pragma unroll
    for (int i = 0; i < 4; ++i) {
        const int row = wave * 4 + i;
        const int* s0 = qw + (otile * 16 + row) * PPR + kq * 512
                      + ((lane ^ (row & 7)) * 4);            // inv-swizzle src
        GLOAD_LDS(s0, &lq[row * 512]);
    }
    #pragma unroll
    for (int i = 0; i < 4; ++i) {
        const int row = wave * 4 + i;
        const int* s1 = qw + (otile * 16 + row) * PPR + kq * 512 + 256
                      + ((lane ^ (row & 7)) * 4);
        GLOAD_LDS(s1, &lq[row * 512 + 256]);
    }
    __builtin_amdgcn_sched_barrier(0);
    asm volatile("s_waitcnt vmcnt(4)" ::: "memory");   // xA + h0 retired (h1 in flight)
    __builtin_amdgcn_sched_barrier(0);
    __builtin_amdgcn_s_barrier();                      // h0 visible to all waves
    __builtin_amdgcn_sched_barrier(0);

    // xB prefetch — overlaps phase-A compute
    asm volatile("global_load_dwordx4 %0, %1, off"             : "=v"(xb0) : "v"(xqb));
    asm volatile("global_load_dwordx4 %0, %1, off offset:1024" : "=v"(xb1) : "v"(xqb));
    asm volatile("global_load_dwordx4 %0, %1, off offset:2048" : "=v"(xb2) : "v"(xqb));
    asm volatile("global_load_dwordx4 %0, %1, off offset:3072" : "=v"(xb3) : "v"(xqb));
    __builtin_amdgcn_sched_barrier(0);

    float4_t acc = {0.f, 0.f, 0.f, 0.f};

// one 32-k-col step: q slot (swizzled ds_read_b128) + dequant + MFMA
#define STEP(XF, BB, T, S2, C2) { \
    const int4_t v = *(const int4_t*)((const char*)lq + ln * 2048 + (BB) \
                    + ((wave * 16 + (((T) * 4 + lk) ^ x3)) << 4)); \
    uint4_t bw; \
    _Pragma("unroll") \
    for (int i = 0; i < 4; ++i) { \
        const unsigned pv = (unsigned)v[i]; \
        const unsigned u = (pv & 0xFu) | ((pv << 12) & 0xF0000u) \
                         | 0x64006400u;            /* {1024+qlo,1024+qhi} */ \
        h2 q = __builtin_bit_cast(h2, u) - k1024;  /* exact {qlo,qhi} */ \
        h2 w = q * (S2) + (C2);                    /* v_pk_fma_f16 */ \
        bw[i] = __builtin_bit_cast(unsigned, w); \
    } \
    acc = __builtin_amdgcn_mfma_f32_16x16x32_f16( \
        (XF), __builtin_bit_cast(half8, bw), acc, 0, 0, 0); }

    STEP(xa0, 0, 0, s2a, c2a)
    STEP(xa1, 0, 1, s2a, c2a)
    STEP(xa2, 0, 2, s2a, c2a)
    STEP(xa3, 0, 3, s2a, c2a)

    __builtin_amdgcn_sched_barrier(0);
    asm volatile("s_waitcnt vmcnt(0)" ::: "memory");   // h1 (and xB) retired
    __builtin_amdgcn_sched_barrier(0);
    __builtin_amdgcn_s_barrier();                      // h1 visible to all waves
    __builtin_amdgcn_sched_barrier(0);

    STEP(xb0, 1024, 0, s2b, c2b)
    STEP(xb1, 1024, 1, s2b, c2b)
    STEP(xb2, 1024, 2, s2b, c2b)
    STEP(xb3, 1024, 3, s2b, c2b)
#undef STEP

    // cross-wave reduce; C/D layout (m89-verified): lane holds D[(l>>4)*4+r][l&15]
    #pragma unroll
    for (int r = 0; r < 4; ++r) red[wave][lk * 4 + r][ln] = acc[r];
    __syncthreads();

    const int row = tid >> 4, col = tid & 15;
    const float sum = red[0][row][col] + red[1][row][col]
                    + red[2][row][col] + red[3][row][col];
    ws_part[(kq * BATCH + row) * OUT_F + otile * 16 + col] = sum;
}

__global__ __launch_bounds__(256) void gptq_reduce(
    const float* __restrict__ ws_part, const float* __restrict__ bias,
    float* __restrict__ out)
{
    const int i4 = (blockIdx.x * 256 + threadIdx.x) * 4;   // 172 blocks exact
    if (i4 >= BATCH * OUT_F) return;
    const int N = BATCH * OUT_F;
    const int o = i4 % OUT_F;                              // OUT_F % 4 == 0
    const float4_t b  = *(const float4_t*)(bias + o);
    const float4_t a0 = *(const float4_t*)(ws_part + i4);
    const float4_t a1 = *(const float4_t*)(ws_part + N + i4);
    const float4_t a2 = *(const float4_t*)(ws_part + 2 * N + i4);
    const float4_t a3 = *(const float4_t*)(ws_part + 3 * N + i4);
    *(float4_t*)((float*)out + i4) = b + a0 + a1 + a2 + a3;
}

// ---- fallback (no workspace): 4-wave single-pass kernel ----
__global__ __launch_bounds__(256) void gptq_gemm_fb(
    const float* __restrict__ x, const int* __restrict__ qw,
    const float* __restrict__ scales, const float* __restrict__ zeros,
    const float* __restrict__ bias, float* __restrict__ out)
{
    const int tid  = threadIdx.x;
    const int lane = tid & 63;
    const int wave = tid >> 6;
    const int otile = blockIdx.x;
    const int ln = lane & 15, lk = lane >> 4;
    const int o = otile * 16 + ln;
    const int kc0 = wave * 1024;

    const int* qbase = qw + o * PPR + (kc0 >> 1) + lk * 4;
    const float* srow = scales + o * GROUPS;
    const float* zrow = zeros  + o * GROUPS;

    float4_t acc = {0.f, 0.f, 0.f, 0.f};
    const h2 k1024 = { (_Float16)1024.0f, (_Float16)1024.0f };

    #pragma unroll
    for (int ch = 0; ch < 4; ++ch) {
        const int cc = kc0 + ch * 256;
        h2 s2[2], c2[2];
        #pragma unroll
        for (int gi = 0; gi < 2; ++gi) {
            const float s  = srow[(cc >> 7) + gi];
            const float c0 = -zrow[(cc >> 7) + gi] * s;
            s2[gi] = cvt2(s, s); c2[gi] = cvt2(c0, c0);
        }
        #pragma unroll
        for (int t = 0; t < 8; ++t) {
            const int4_t v = *(const int4_t*)(qbase + ch * 128 + t * 16);
            const float* xq = x + ln * IN_F + cc + t * 32 + lk * 8;
            const float4_t a0 = *(const float4_t*)(xq);
            const float4_t a1 = *(const float4_t*)(xq + 4);
            half8 af;
            h2 p0 = cvt2(a0.x, a0.y), p1 = cvt2(a0.z, a0.w);
            h2 p2 = cvt2(a1.x, a1.y), p3 = cvt2(a1.z, a1.w);
            af[0]=p0[0]; af[1]=p0[1]; af[2]=p1[0]; af[3]=p1[1];
            af[4]=p2[0]; af[5]=p2[1]; af[6]=p3[0]; af[7]=p3[1];
            const int gi = t >> 2;
            uint4_t bw;
            #pragma unroll
            for (int i = 0; i < 4; ++i) {
                const unsigned pv = (unsigned)v[i];
                const unsigned u = (pv & 0xFu) | ((pv << 12) & 0xF0000u)
                                 | 0x64006400u;
                h2 q = __builtin_bit_cast(h2, u) - k1024;
                h2 w = q * s2[gi] + c2[gi];
                bw[i] = __builtin_bit_cast(unsigned, w);
            }
            acc = __builtin_amdgcn_mfma_f32_16x16x32_f16(
                af, __builtin_bit_cast(half8, bw), acc, 0, 0, 0);
        }
    }

    __shared__ float red[4][16][17];
    #pragma unroll
    for (int r = 0; r < 4; ++r) red[wave][lk * 4 + r][ln] = acc[r];
    __syncthreads();
    const int row = tid >> 4, col = tid & 15;
    const float sum = red[0][row][col] + red[1][row][col]
                    + red[2][row][col] + red[3][row][col];
    const int oo = otile * 16 + col;
    out[row * OUT_F + oo] = sum + bias[oo];
}

extern "C" void kernel_launch(void* const* d_in, const int* in_sizes, int n_in,
                              void* d_out, int out_size, void* d_ws, size_t ws_size,
                              hipStream_t stream) {
    const float* x      = (const float*)d_in[0];
    const int*   qwgt   = (const int*)d_in[1];
    const float* scales = (const float*)d_in[2];
    const float* zeros  = (const float*)d_in[3];
    const float* bias   = (const float*)d_in[4];
    float* out = (float*)d_out;

    const int nOTiles = OUT_F / 16;                    // 688
    const size_t need = (size_t)8 << 20;

    if (d_ws && ws_size >= need) {
        float*    ws_part = (float*)d_ws;                         // 2.75 MB
        _Float16* xp      = (_Float16*)((char*)d_ws + (4 << 20)); // 128 KB
        hipLaunchKernelGGL(xcvt_perm, dim3(32), dim3(256), 0, stream, x, xp);
        hipLaunchKernelGGL(gptq_gemm_w, dim3(nOTiles * 4), dim3(256), 0, stream,
                           xp, qwgt, scales, zeros, ws_part);
        hipLaunchKernelGGL(gptq_reduce, dim3((BATCH * OUT_F / 4 + 255) / 256),
                           dim3(256), 0, stream, ws_part, bias, out);
    } else {
        hipLaunchKernelGGL(gptq_gemm_fb, dim3(nOTiles), dim3(256), 0, stream,
                           x, qwgt, scales, zeros, bias, out);
    }
}

// Round 10
// 29.903 us; speedup vs baseline: 2.4585x; 1.0136x over previous
//
#include <hip/hip_runtime.h>
#include <hip/hip_fp16.h>

#define IN_F   4096
#define OUT_F  11008
#define BATCH  16
#define GROUPS 32                    // 4096 / 128
#define PPR    2048                  // packed int32 per output row (IN_F/2)

typedef __attribute__((ext_vector_type(8))) _Float16 half8;
typedef __attribute__((ext_vector_type(2))) _Float16 h2;
typedef __attribute__((ext_vector_type(4))) float    float4_t;
typedef __attribute__((ext_vector_type(4))) int      int4_t;
typedef __attribute__((ext_vector_type(4))) unsigned uint4_t;

__device__ inline h2 cvt2(float a, float b) {
    return __builtin_bit_cast(h2, __builtin_amdgcn_cvt_pkrtz(a, b));
}

// async global->LDS, 16B per lane, dest = uniform base + lane*16
#define GLOAD_LDS(srcp, ldsp) \
    __builtin_amdgcn_global_load_lds( \
        (const __attribute__((address_space(1))) void*)(srcp), \
        (__attribute__((address_space(3))) void*)(ldsp), 16, 0, 0)

// ---- pre-pass: x (16x4096 f32) -> f16 table in FRAGMENT order ----
// step s (32 k-cols), lane l: xp[s*512 + l*8 .. +8) = f16 x[b=l&15]
// [k = s*32 + (l>>4)*8 .. +8). Gemm A-fragment load = ONE contiguous 1KB req.
__global__ __launch_bounds__(256) void xcvt_perm(const float* __restrict__ x,
                                                 _Float16* __restrict__ xp) {
    const int T = blockIdx.x * 256 + threadIdx.x;   // 8192 threads
    const int step = T >> 6, lane = T & 63;
    const int b = lane & 15, k = step * 32 + (lane >> 4) * 8;
    const float4_t a0 = *(const float4_t*)(x + b * IN_F + k);
    const float4_t a1 = *(const float4_t*)(x + b * IN_F + k + 4);
    half8 h;
    h2 p0 = cvt2(a0.x, a0.y), p1 = cvt2(a0.z, a0.w);
    h2 p2 = cvt2(a1.x, a1.y), p3 = cvt2(a1.z, a1.w);
    h[0]=p0[0]; h[1]=p0[1]; h[2]=p1[0]; h[3]=p1[1];
    h[4]=p2[0]; h[5]=p2[1]; h[6]=p3[0]; h[7]=p3[1];
    *(half8*)(xp + step * 512 + lane * 8) = h;
}

// ---- single-pass gemm: block = otile, FULL K in 4 chunks of 1024 cols.
// LDS double-buffer 2x32KB. Wave w computes cols [c*1024+w*256, +256) of each
// chunk c (groups c*8+w*2, +1), accumulating over all K; 4-way cross-wave
// reduce + bias + direct store. Counted vmcnt keeps the next chunk's 16
// VMEM ops in flight across every barrier (drain only before the last chunk).
__global__ __launch_bounds__(256) void gptq_gemm_full(
    const _Float16* __restrict__ xp, const int* __restrict__ qw,
    const float* __restrict__ scales, const float* __restrict__ zeros,
    const float* __restrict__ bias, float* __restrict__ out)
{
    __shared__ int   lq[2][16 * 512];    // 64 KB, swizzled q tiles
    __shared__ float red[4][16][17];

    const int tid  = threadIdx.x;
    const int lane = tid & 63, wave = tid >> 6;
    const int otile = blockIdx.x;
    const int ln = lane & 15, lk = lane >> 4;
    const int o  = otile * 16 + ln;
    const int x3 = ln & 7;

    // 8 (s,z) pairs for this wave: group g = c*8 + wave*2 + gi
    h2 s2g[8], c2g[8];
    #pragma unroll
    for (int c = 0; c < 4; ++c) {
        #pragma unroll
        for (int gi = 0; gi < 2; ++gi) {
            const int g = c * 8 + wave * 2 + gi;
            const float s = scales[o * GROUPS + g];
            const float z = zeros [o * GROUPS + g];
            s2g[c * 2 + gi] = cvt2(s, s);
            c2g[c * 2 + gi] = cvt2(-z * s, -z * s);   // w = q*s + (-z*s)
        }
    }
    const h2 k1024 = { (_Float16)1024.0f, (_Float16)1024.0f };

    asm volatile("s_waitcnt vmcnt(0)" ::: "memory");   // scalar loads retired
    __builtin_amdgcn_sched_barrier(0);                 // -> vmcnt counts exact

    half8 xv[2][8];
    float4_t acc = {0.f, 0.f, 0.f, 0.f};

// stage chunk C's 16 rows (this wave: 4 rows x 2 halves), src inv-swizzled
#define STAGE(C, BUF) { \
    _Pragma("unroll") \
    for (int i = 0; i < 4; ++i) { \
        const int row = wave * 4 + i; \
        const int* s0 = qw + (otile * 16 + row) * PPR + (C) * 512 \
                      + ((lane ^ (row & 7)) * 4); \
        GLOAD_LDS(s0, &lq[BUF][row * 512]); \
        GLOAD_LDS(s0 + 256, &lq[BUF][row * 512 + 256]); \
    } \
    __builtin_amdgcn_sched_barrier(0); }

// 8 x-fragment loads for chunk C (steps c*32 + wave*8 + t), contiguous 1KB each
#define XLOAD(C, BUF) { \
    const char* xc = (const char*)xp + ((C) * 32 + wave * 8) * 1024 + lane * 16; \
    asm volatile("global_load_dwordx4 %0, %1, off"             : "=v"(xv[BUF][0]) : "v"(xc)); \
    asm volatile("global_load_dwordx4 %0, %1, off offset:1024" : "=v"(xv[BUF][1]) : "v"(xc)); \
    asm volatile("global_load_dwordx4 %0, %1, off offset:2048" : "=v"(xv[BUF][2]) : "v"(xc)); \
    asm volatile("global_load_dwordx4 %0, %1, off offset:3072" : "=v"(xv[BUF][3]) : "v"(xc)); \
    const char* xd = xc + 4096; \
    asm volatile("global_load_dwordx4 %0, %1, off"             : "=v"(xv[BUF][4]) : "v"(xd)); \
    asm volatile("global_load_dwordx4 %0, %1, off offset:1024" : "=v"(xv[BUF][5]) : "v"(xd)); \
    asm volatile("global_load_dwordx4 %0, %1, off offset:2048" : "=v"(xv[BUF][6]) : "v"(xd)); \
    asm volatile("global_load_dwordx4 %0, %1, off offset:3072" : "=v"(xv[BUF][7]) : "v"(xd)); \
    __builtin_amdgcn_sched_barrier(0); }

#define WAITV16 { asm volatile("s_waitcnt vmcnt(16)" ::: "memory"); \
                  __builtin_amdgcn_sched_barrier(0); }
#define WAITV0  { asm volatile("s_waitcnt vmcnt(0)"  ::: "memory"); \
                  __builtin_amdgcn_sched_barrier(0); }
#define BARR    { __builtin_amdgcn_s_barrier(); \
                  __builtin_amdgcn_sched_barrier(0); }

// 8 steps of chunk C from buffer BUF: swizzled ds_read_b128 + dequant + MFMA
#define COMPUTE(C, BUF) { \
    _Pragma("unroll") \
    for (int t = 0; t < 8; ++t) { \
        const int4_t v = *(const int4_t*)((const char*)lq \
            + (BUF) * 32768 + ln * 2048 + (wave >> 1) * 1024 \
            + ((((wave & 1) * 32 + t * 4 + lk) ^ x3) << 4)); \
        const int sg = (C) * 2 + (t >> 2); \
        uint4_t bw; \
        _Pragma("unroll") \
        for (int i = 0; i < 4; ++i) { \
            const unsigned pv = (unsigned)v[i]; \
            const unsigned u = (pv & 0xFu) | ((pv << 12) & 0xF0000u) \
                             | 0x64006400u;            /* {1024+qlo,1024+qhi} */ \
            h2 q = __builtin_bit_cast(h2, u) - k1024;  /* exact {qlo,qhi} */ \
            h2 w = q * s2g[sg] + c2g[sg];              /* v_pk_fma_f16 */ \
            bw[i] = __builtin_bit_cast(unsigned, w); \
        } \
        acc = __builtin_amdgcn_mfma_f32_16x16x32_f16( \
            xv[BUF][t], __builtin_bit_cast(half8, bw), acc, 0, 0, 0); \
    } }

    STAGE(0, 0) XLOAD(0, 0)      // 16 in flight
    STAGE(1, 1) XLOAD(1, 1)      // 32 in flight
    WAITV16 BARR                 // chunk 0 ready (chunk 1 still in flight)
    COMPUTE(0, 0)
    BARR                         // all waves done reading buf0
    STAGE(2, 0) XLOAD(2, 0)      // 32 in flight
    WAITV16 BARR                 // chunk 1 ready (chunk 2 in flight)
    COMPUTE(1, 1)
    BARR                         // buf1 free
    STAGE(3, 1) XLOAD(3, 1)      // 32 in flight
    WAITV16 BARR                 // chunk 2 ready (chunk 3 in flight)
    COMPUTE(2, 0)
    WAITV0 BARR                  // chunk 3 ready
    COMPUTE(3, 1)

#undef STAGE
#undef XLOAD
#undef WAITV16
#undef WAITV0
#undef BARR
#undef COMPUTE

    // cross-wave k-reduce; C/D layout (m89-verified): lane holds D[(l>>4)*4+r][l&15]
    #pragma unroll
    for (int r = 0; r < 4; ++r) red[wave][lk * 4 + r][ln] = acc[r];
    __syncthreads();

    const int row = tid >> 4, col = tid & 15;
    const float sum = red[0][row][col] + red[1][row][col]
                    + red[2][row][col] + red[3][row][col];
    const int oo = otile * 16 + col;
    out[row * OUT_F + oo] = sum + bias[oo];
}

// ---- fallback (no workspace): 4-wave single-pass kernel ----
__global__ __launch_bounds__(256) void gptq_gemm_fb(
    const float* __restrict__ x, const int* __restrict__ qw,
    const float* __restrict__ scales, const float* __restrict__ zeros,
    const float* __restrict__ bias, float* __restrict__ out)
{
    const int tid  = threadIdx.x;
    const int lane = tid & 63;
    const int wave = tid >> 6;
    const int otile = blockIdx.x;
    const int ln = lane & 15, lk = lane >> 4;
    const int o = otile * 16 + ln;
    const int kc0 = wave * 1024;

    const int* qbase = qw + o * PPR + (kc0 >> 1) + lk * 4;
    const float* srow = scales + o * GROUPS;
    const float* zrow = zeros  + o * GROUPS;

    float4_t acc = {0.f, 0.f, 0.f, 0.f};
    const h2 k1024 = { (_Float16)1024.0f, (_Float16)1024.0f };

    #pragma unroll
    for (int ch = 0; ch < 4; ++ch) {
        const int cc = kc0 + ch * 256;
        h2 s2[2], c2[2];
        #pragma unroll
        for (int gi = 0; gi < 2; ++gi) {
            const float s  = srow[(cc >> 7) + gi];
            const float c0 = -zrow[(cc >> 7) + gi] * s;
            s2[gi] = cvt2(s, s); c2[gi] = cvt2(c0, c0);
        }
        #pragma unroll
        for (int t = 0; t < 8; ++t) {
            const int4_t v = *(const int4_t*)(qbase + ch * 128 + t * 16);
            const float* xq = x + ln * IN_F + cc + t * 32 + lk * 8;
            const float4_t a0 = *(const float4_t*)(xq);
            const float4_t a1 = *(const float4_t*)(xq + 4);
            half8 af;
            h2 p0 = cvt2(a0.x, a0.y), p1 = cvt2(a0.z, a0.w);
            h2 p2 = cvt2(a1.x, a1.y), p3 = cvt2(a1.z, a1.w);
            af[0]=p0[0]; af[1]=p0[1]; af[2]=p1[0]; af[3]=p1[1];
            af[4]=p2[0]; af[5]=p2[1]; af[6]=p3[0]; af[7]=p3[1];
            const int gi = t >> 2;
            uint4_t bw;
            #pragma unroll
            for (int i = 0; i < 4; ++i) {
                const unsigned pv = (unsigned)v[i];
                const unsigned u = (pv & 0xFu) | ((pv << 12) & 0xF0000u)
                                 | 0x64006400u;
                h2 q = __builtin_bit_cast(h2, u) - k1024;
                h2 w = q * s2[gi] + c2[gi];
                bw[i] = __builtin_bit_cast(unsigned, w);
            }
            acc = __builtin_amdgcn_mfma_f32_16x16x32_f16(
                af, __builtin_bit_cast(half8, bw), acc, 0, 0, 0);
        }
    }

    __shared__ float red[4][16][17];
    #pragma unroll
    for (int r = 0; r < 4; ++r) red[wave][lk * 4 + r][ln] = acc[r];
    __syncthreads();
    const int row = tid >> 4, col = tid & 15;
    const float sum = red[0][row][col] + red[1][row][col]
                    + red[2][row][col] + red[3][row][col];
    const int oo = otile * 16 + col;
    out[row * OUT_F + oo] = sum + bias[oo];
}

extern "C" void kernel_launch(void* const* d_in, const int* in_sizes, int n_in,
                              void* d_out, int out_size, void* d_ws, size_t ws_size,
                              hipStream_t stream) {
    const float* x      = (const float*)d_in[0];
    const int*   qwgt   = (const int*)d_in[1];
    const float* scales = (const float*)d_in[2];
    const float* zeros  = (const float*)d_in[3];
    const float* bias   = (const float*)d_in[4];
    float* out = (float*)d_out;

    const int nOTiles = OUT_F / 16;                    // 688

    if (d_ws && ws_size >= (size_t)(1 << 20)) {
        _Float16* xp = (_Float16*)d_ws;                // 128 KB f16 x table
        hipLaunchKernelGGL(xcvt_perm, dim3(32), dim3(256), 0, stream, x, xp);
        hipLaunchKernelGGL(gptq_gemm_full, dim3(nOTiles), dim3(256), 0, stream,
                           xp, qwgt, scales, zeros, bias, out);
    } else {
        hipLaunchKernelGGL(gptq_gemm_fb, dim3(nOTiles), dim3(256), 0, stream,
                           x, qwgt, scales, zeros, bias, out);
    }
}